// Round 13
// baseline (3298.078 us; speedup 1.0000x reference)
//
#include <hip/hip_runtime.h>
#include <cstdint>
#include <cstddef>

typedef _Float16 f16;
typedef _Float16 f16x8 __attribute__((ext_vector_type(8)));
typedef _Float16 f16x4 __attribute__((ext_vector_type(4)));
typedef float    f32x4 __attribute__((ext_vector_type(4)));

#define AS1 __attribute__((address_space(1)))
#define AS3 __attribute__((address_space(3)))

static constexpr int BB = 8;      // batch
static constexpr int SS = 2048;   // sequence
static constexpr int DD = 1024;   // model dim
static constexpr int MTOT = BB * SS; // 16384

// ---------------------------------------------------------------------------
// fused cast f32->f16 for both inputs + qkv bias concat (one dispatch)
// ---------------------------------------------------------------------------
__global__ __launch_bounds__(256) void cast2_f32_f16(
    const float* __restrict__ s1, const float* __restrict__ s2,
    f16* __restrict__ d1, f16* __restrict__ d2, int n4,
    const float* __restrict__ bq, const float* __restrict__ bk,
    const float* __restrict__ bv, float* __restrict__ qkvb) {
  int i = blockIdx.x * 256 + threadIdx.x;
  if (i < 3 * DD)
    qkvb[i] = (i < DD) ? bq[i] : (i < 2 * DD) ? bk[i - DD] : bv[i - 2 * DD];
  const float* s;
  f16* d;
  int j;
  if (i < n4) { s = s1; d = d1; j = i; }
  else        { s = s2; d = d2; j = i - n4; if (j >= n4) return; }
  const float4 f = reinterpret_cast<const float4*>(s)[j];
  f16x4 o = { (f16)f.x, (f16)f.y, (f16)f.z, (f16)f.w };
  reinterpret_cast<f16x4*>(d)[j] = o;
}

// ---------------------------------------------------------------------------
// fused weight transpose + cast for 5 weights: WT[n][k] = (f16)W[k][n]
// ---------------------------------------------------------------------------
__global__ __launch_bounds__(256) void transpose_cast_wt5(
    const float* __restrict__ W0, const float* __restrict__ W1,
    const float* __restrict__ W2, const float* __restrict__ W3,
    const float* __restrict__ W4,
    f16* __restrict__ D0, f16* __restrict__ D1, f16* __restrict__ D2,
    f16* __restrict__ D3, f16* __restrict__ D4) {
  __shared__ float tile[32][33];
  const float* W;
  f16* Dst;
  switch (blockIdx.z) {
    case 0: W = W0; Dst = D0; break;
    case 1: W = W1; Dst = D1; break;
    case 2: W = W2; Dst = D2; break;
    case 3: W = W3; Dst = D3; break;
    default: W = W4; Dst = D4; break;
  }
  const int bx = blockIdx.x * 32;
  const int by = blockIdx.y * 32;
  const int tx = threadIdx.x & 31;
  const int ty = threadIdx.x >> 5;
  for (int i = ty; i < 32; i += 8) tile[i][tx] = W[(size_t)(by + i) * DD + bx + tx];
  __syncthreads();
  for (int i = ty; i < 32; i += 8)
    Dst[(size_t)(bx + i) * DD + by + tx] = (f16)tile[tx][i];
}

// ---------------------------------------------------------------------------
// batched f16 transpose with src stride: dst[b][c][r] = src[b*sBat + r*sStr + c]
// ---------------------------------------------------------------------------
__global__ __launch_bounds__(256) void transpose_f16_batch(const f16* __restrict__ src,
                                                           f16* __restrict__ dst,
                                                           int R, int C, int sStr,
                                                           size_t sBat) {
  __shared__ f16 tile[32][33];
  src += (size_t)blockIdx.z * sBat;
  dst += (size_t)blockIdx.z * R * C;
  const int bx = blockIdx.x * 32;
  const int by = blockIdx.y * 32;
  const int tx = threadIdx.x & 31;
  const int ty = threadIdx.x >> 5;
  for (int i = ty; i < 32; i += 8) tile[i][tx] = src[(size_t)(by + i) * sStr + bx + tx];
  __syncthreads();
  for (int i = ty; i < 32; i += 8) dst[(size_t)(bx + i) * R + by + tx] = tile[tx][i];
}

// ---------------------------------------------------------------------------
// 256x256 GEMM, 16x16x32 MFMA — r13: SINGLE-buffered LDS (64 KB) -> 2 blocks
// per CU (16 waves), simple 2-barrier loop (m97-class). Cross-block
// anti-phase overlap replaces intra-block pipelining: block A's MFMA region
// co-runs with block B's LDS/stage region (separate pipes, m114).
// stageA/stageB/lda/ldb/swizzle/epilogues identical to r12 (verified).
// EPI 0: fused QKV | 1 ->f32 | 2 ->f16 | 3 +bias+resid | 4 relu+W2 dot
// ---------------------------------------------------------------------------
template <int EPI>
__global__ __launch_bounds__(512, 4) void gemm8(
    const f16* __restrict__ A, const f16* __restrict__ A2, int zsplit,
    const f16* __restrict__ Aq, void* __restrict__ CoutQ, int qn,
    const f16* __restrict__ BT, void* __restrict__ Cout,
    const float* __restrict__ bias, const float* __restrict__ resid,
    int N, int K, int ldA, int ldB, int gx,
    size_t Abat, size_t Bbat, size_t Cbat) {
  __shared__ f16 smA[256 * 64];
  __shared__ f16 smB[256 * 64];

  const int bz = blockIdx.z;
  const f16* Ab = (zsplit && bz >= zsplit) ? A2 + (size_t)(bz - zsplit) * Abat
                                           : A + (size_t)bz * Abat;
  BT += (size_t)bz * Bbat;

  // bijective XCD swizzle (m204)
  const int nwg = gridDim.x;
  const int q = nwg >> 3, r = nwg & 7;
  const int xcd = blockIdx.x & 7, lin = blockIdx.x >> 3;
  const int wg = (xcd < r ? xcd * (q + 1) : r * (q + 1) + (xcd - r) * q) + lin;
  const int n0 = (wg % gx) * 256;
  const int m0 = (wg / gx) * 256;

  if (EPI == 0 && n0 < qn) Ab = Aq;   // fused projection A-select (wave-uniform)

  const int tid = threadIdx.x;
  const int w = tid >> 6, lane = tid & 63;
  const int wr = w >> 2, wc = w & 3;   // 2 x 4 wave grid
  const int lg = lane >> 4, lr = lane & 15;
  const int nt = K >> 6;               // K-tiles (K multiple of 64)

  f32x4 acc[8][4] = {};
  f16x8 alo[4][2], ahi[4][2], bfr[2][2];

  // stage one 128x64 half-tile; LDS linear dest, source granule pre-swizzled
  auto stageA = [&](int t, int h) {
#pragma unroll
    for (int l = 0; l < 2; ++l) {
      const int cb = l * 512 + w * 64;
      const int c = cb + lane;
      const int rr = c >> 3;
      const int g = (c & 7) ^ (rr & 7);
      const f16* src = Ab + (size_t)(m0 + h * 128 + rr) * ldA + t * 64 + g * 8;
      __builtin_amdgcn_global_load_lds((const AS1 void*)src,
          (AS3 void*)(&smA[(h * 1024 + cb) * 8]), 16, 0, 0);
    }
  };
  auto stageB = [&](int t, int h) {
#pragma unroll
    for (int l = 0; l < 2; ++l) {
      const int cb = l * 512 + w * 64;
      const int c = cb + lane;
      const int rr = c >> 3;
      const int g = (c & 7) ^ (rr & 7);
      const f16* src = BT + (size_t)(n0 + h * 128 + rr) * ldB + t * 64 + g * 8;
      __builtin_amdgcn_global_load_lds((const AS1 void*)src,
          (AS3 void*)(&smB[(h * 1024 + cb) * 8]), 16, 0, 0);
    }
  };
  // r4-verified 16x16 fragment reads (0 bank conflicts measured)
  auto lda = [&](f16x8 (&dst)[4][2], int mh) {
#pragma unroll
    for (int i = 0; i < 4; ++i) {
      const int rrow = wr * 128 + (mh * 4 + i) * 16 + lr;
#pragma unroll
      for (int kh = 0; kh < 2; ++kh) {
        const int kg = (kh * 4 + lg) ^ (rrow & 7);
        dst[i][kh] = *(const f16x8*)(&smA[rrow * 64 + kg * 8]);
      }
    }
  };
  auto ldb = [&](int nh) {
#pragma unroll
    for (int j = 0; j < 2; ++j) {
      const int nrow = wc * 64 + (nh * 2 + j) * 16 + lr;
#pragma unroll
      for (int kh = 0; kh < 2; ++kh) {
        const int kg = (kh * 4 + lg) ^ (nrow & 7);
        bfr[j][kh] = *(const f16x8*)(&smB[nrow * 64 + kg * 8]);
      }
    }
  };
  auto mma = [&](const f16x8 (&a)[4][2], int mh, int nh) {
#pragma unroll
    for (int i = 0; i < 4; ++i)
#pragma unroll
      for (int j = 0; j < 2; ++j)
#pragma unroll
        for (int kh = 0; kh < 2; ++kh)
          acc[mh * 4 + i][nh * 2 + j] = __builtin_amdgcn_mfma_f32_16x16x32_f16(
              a[i][kh], bfr[j][kh], acc[mh * 4 + i][nh * 2 + j], 0, 0, 0);
  };

  // m97-class 2-barrier loop. __syncthreads provides vmcnt(0)+lgkmcnt(0)
  // drains: barrier-1 guarantees staged data landed; barrier-2 guarantees all
  // waves' ds_reads of tile t completed (reads drain before dependent MFMAs
  // issue) before anyone overwrites the buffer with tile t+1.
  for (int t = 0; t < nt; ++t) {
    stageA(t, 0); stageA(t, 1);
    stageB(t, 0); stageB(t, 1);
    __syncthreads();
    ldb(0); lda(alo, 0); lda(ahi, 1);
    mma(alo, 0, 0); mma(ahi, 1, 0);
    ldb(1);
    mma(ahi, 1, 1); mma(alo, 0, 1);
    __syncthreads();
  }

  if (EPI == 4) {
    // fused relu + W2 (in `resid`) dot -> partials[16][MTOT] (each written once)
    float* part = (float*)Cout;
    const int cq = (n0 >> 6) + wc;
#pragma unroll
    for (int I = 0; I < 8; ++I) {
#pragma unroll
      for (int rr = 0; rr < 4; ++rr) {
        const int row = m0 + wr * 128 + I * 16 + lg * 4 + rr;
        float s = 0.f;
#pragma unroll
        for (int J = 0; J < 4; ++J) {
          const int col = n0 + wc * 64 + J * 16 + lr;
          float v = acc[I][J][rr] + bias[col];
          v = fmaxf(v, 0.f);
          s += v * resid[col];
        }
#pragma unroll
        for (int o = 1; o < 16; o <<= 1) s += __shfl_xor(s, o);
        if (lr == 0) part[(size_t)cq * MTOT + row] = s;
      }
    }
    return;
  }

  // epilogue: D mapping col=lane&15, row=(lane>>4)*4+r
  const bool isQ = (EPI == 0) && (n0 < qn);
#pragma unroll
  for (int I = 0; I < 8; ++I) {
    const int row = m0 + wr * 128 + I * 16 + lg * 4;
#pragma unroll
    for (int J = 0; J < 4; ++J) {
      const int col = n0 + wc * 64 + J * 16 + lr;
      float bval = 0.f;
      if (EPI == 0 || EPI == 3) bval = bias[col];
#pragma unroll
      for (int rr = 0; rr < 4; ++rr) {
        float v = acc[I][J][rr] + bval;
        if (EPI == 0) {
          if (isQ) ((f16*)CoutQ)[(size_t)(row + rr) * qn + col] = (f16)v;
          else     ((f16*)Cout)[(size_t)(row + rr) * N + (col - qn)] = (f16)v;
        } else {
          const size_t idx = (size_t)(row + rr) * N + col;
          if (EPI == 3) v += resid[idx];
          if (EPI == 1)
            ((float*)Cout)[(size_t)bz * Cbat + idx] = v;
          else
            ((f16*)Cout)[(size_t)bz * Cbat + idx] = (f16)v;
        }
      }
    }
  }
}

// ---------------------------------------------------------------------------
// row softmax: one block per row of 2048 fp32 scores -> f16 probabilities
// ---------------------------------------------------------------------------
__global__ __launch_bounds__(256) void softmax_rows(const float* __restrict__ Sc,
                                                    f16* __restrict__ P) {
  const size_t row = blockIdx.x;
  const float* x = Sc + row * SS;
  f16* p = P + row * SS;
  const int t = threadIdx.x;
  const int wid = t >> 6, lane = t & 63;
  __shared__ float red[8];

  float4 va = reinterpret_cast<const float4*>(x)[t];
  float4 vb = reinterpret_cast<const float4*>(x)[256 + t];
  float mx = fmaxf(fmaxf(fmaxf(va.x, va.y), fmaxf(va.z, va.w)),
                   fmaxf(fmaxf(vb.x, vb.y), fmaxf(vb.z, vb.w)));
#pragma unroll
  for (int o = 32; o >= 1; o >>= 1) mx = fmaxf(mx, __shfl_xor(mx, o));
  if (lane == 0) red[wid] = mx;
  __syncthreads();
  mx = fmaxf(fmaxf(red[0], red[1]), fmaxf(red[2], red[3]));

  va.x = __expf(va.x - mx); va.y = __expf(va.y - mx);
  va.z = __expf(va.z - mx); va.w = __expf(va.w - mx);
  vb.x = __expf(vb.x - mx); vb.y = __expf(vb.y - mx);
  vb.z = __expf(vb.z - mx); vb.w = __expf(vb.w - mx);
  float sum = (va.x + va.y) + (va.z + va.w) + (vb.x + vb.y) + (vb.z + vb.w);
#pragma unroll
  for (int o = 32; o >= 1; o >>= 1) sum += __shfl_xor(sum, o);
  if (lane == 0) red[4 + wid] = sum;
  __syncthreads();
  sum = red[4] + red[5] + red[6] + red[7];
  const float inv = 1.0f / sum;
  f16x4 pa = { (f16)(va.x * inv), (f16)(va.y * inv),
               (f16)(va.z * inv), (f16)(va.w * inv) };
  f16x4 pb = { (f16)(vb.x * inv), (f16)(vb.y * inv),
               (f16)(vb.z * inv), (f16)(vb.w * inv) };
  reinterpret_cast<f16x4*>(p)[t] = pa;
  reinterpret_cast<f16x4*>(p)[256 + t] = pb;
}

// ---------------------------------------------------------------------------
// out[i] = sum_c partials[c][i] + b2
// ---------------------------------------------------------------------------
__global__ __launch_bounds__(256) void reduce_out(const float* __restrict__ part,
                                                  const float* __restrict__ b2,
                                                  float* __restrict__ out) {
  const int i = blockIdx.x * 256 + threadIdx.x;
  float s = 0.f;
#pragma unroll
  for (int c = 0; c < 16; ++c) s += part[(size_t)c * MTOT + i];
  out[i] = s + b2[0];
}

// ---------------------------------------------------------------------------
extern "C" void kernel_launch(void* const* d_in, const int* in_sizes, int n_in,
                              void* d_out, int out_size, void* d_ws, size_t ws_size,
                              hipStream_t stream) {
  const float* vis = (const float*)d_in[0];
  const float* aud = (const float*)d_in[1];
  const float* Wq = (const float*)d_in[2];
  const float* bq = (const float*)d_in[3];
  const float* Wk = (const float*)d_in[4];
  const float* bk = (const float*)d_in[5];
  const float* Wv = (const float*)d_in[6];
  const float* bv = (const float*)d_in[7];
  const float* Wo = (const float*)d_in[8];
  const float* bo = (const float*)d_in[9];
  const float* W1 = (const float*)d_in[10];
  const float* b1 = (const float*)d_in[11];
  const float* W2 = (const float*)d_in[12];
  const float* b2 = (const float*)d_in[13];
  float* out = (float*)d_out;
  (void)in_sizes; (void)n_in; (void)out_size;

  char* ws = (char*)d_ws;
  size_t off = 0;
  auto carve = [&](size_t bytes) -> void* {
    void* p = ws + off;
    off += (bytes + 255) & ~(size_t)255;
    return p;
  };
  const size_t wtB = (size_t)DD * DD * sizeof(f16);     // 2 MB
  const size_t bufB = (size_t)MTOT * DD * sizeof(f16);  // 33.55 MB
  // QKVT rows 0..1023 = Wq^T, 1024..2047 = Wk^T, 2048..3071 = Wv^T
  f16* QKVT = (f16*)carve(3 * wtB);
  f16* WoT = (f16*)carve(wtB);
  f16* W1T = (f16*)carve(wtB);
  float* qkvb = (float*)carve(3 * DD * sizeof(float));  // 12 KB bias concat
  f16* slot1 = (f16*)carve(bufB);    // VIS16 -> VT16 -> H16
  f16* slot2 = (f16*)carve(bufB);    // AUD16 -> P0 -> partials
  f16* slot3 = (f16*)carve(bufB);    // Q16 -> P1 (or ATT in fallback)
  f16* KV16 = (f16*)carve(2 * bufB); // fused K|V projection [16384][2048]

  const size_t rem = (ws_size > off) ? ws_size - off : 0;
  const size_t needMain = (size_t)4 * SS * SS * sizeof(float) + 512; // 67.1 MB

  f16* VIS16 = slot1;
  f16* AUD16 = slot2;
  f16* Q16 = slot3;
  f16* VT16 = slot1;
  f16* P0 = slot2;
  f16* P1 = slot3;
  f16* H16 = slot1;
  float* partials = (float*)slot2;

  const dim3 blk(256);
  const dim3 blk8(512);
  const int n4 = MTOT * DD / 4;

  // 1. cast both inputs to fp16 + build qkv bias concat (one dispatch)
  cast2_f32_f16<<<dim3((2 * n4 + 255) / 256), blk, 0, stream>>>(
      vis, aud, VIS16, AUD16, n4, bq, bk, bv, qkvb);

  // 2. transpose + cast all 5 weights (one dispatch)
  transpose_cast_wt5<<<dim3(DD / 32, DD / 32, 5), blk, 0, stream>>>(
      Wq, Wk, Wv, Wo, W1, QKVT, QKVT + (size_t)DD * DD,
      QKVT + (size_t)2 * DD * DD, WoT, W1T);

  // 3. fused Q|K|V projection: one dispatch, N=3072, A/C select by n0
  gemm8<0><<<dim3(12 * 64, 1, 1), blk8, 0, stream>>>(
      AUD16, nullptr, 0, VIS16, Q16, DD, QKVT, KV16, qkvb, nullptr,
      2 * DD, DD, DD, DD, 12, 0, 0, 0);

  // 4. V -> VT per batch (V = KV16 cols 1024.., row stride 2048)
  transpose_f16_batch<<<dim3(DD / 32, SS / 32, BB), blk, 0, stream>>>(
      KV16 + DD, VT16, SS, DD, 2 * DD, (size_t)SS * 2 * DD);

  if (rem >= needMain) {
    float* S32 = (float*)carve((size_t)4 * SS * SS * sizeof(float)); // 67.1 MB
    f16* ATT16 = (f16*)S32;  // reused after softmax chunk 2 consumes S32
    // 5-6. scores -> softmax, batches 0-3 then 4-7
    gemm8<1><<<dim3((SS / 256) * (SS / 256), 1, 4), blk8, 0, stream>>>(
        Q16, nullptr, 0, nullptr, nullptr, 0, KV16, S32, nullptr, nullptr,
        SS, DD, DD, 2 * DD, SS / 256,
        (size_t)SS * DD, (size_t)SS * 2 * DD, (size_t)SS * SS);
    softmax_rows<<<dim3(4 * SS), blk, 0, stream>>>(S32, P0);
    gemm8<1><<<dim3((SS / 256) * (SS / 256), 1, 4), blk8, 0, stream>>>(
        Q16 + (size_t)4 * SS * DD, nullptr, 0, nullptr, nullptr, 0,
        KV16 + (size_t)4 * SS * 2 * DD, S32, nullptr, nullptr,
        SS, DD, DD, 2 * DD, SS / 256,
        (size_t)SS * DD, (size_t)SS * 2 * DD, (size_t)SS * SS);
    softmax_rows<<<dim3(4 * SS), blk, 0, stream>>>(S32, P1);
    // 7. PV: one full-width dispatch, z=8, split-P A base; ATT overwrites S32
    gemm8<2><<<dim3((DD / 256) * (SS / 256), 1, 8), blk8, 0, stream>>>(
        P0, P1, 4, nullptr, nullptr, 0, VT16, ATT16, nullptr, nullptr,
        DD, SS, SS, SS, DD / 256,
        (size_t)SS * SS, (size_t)DD * SS, (size_t)SS * DD);
    // 8. h = attended @ Wo + bo + visual(residual, fp32) -> slot1 (VT dead)
    gemm8<3><<<dim3(4 * 64, 1, 1), blk8, 0, stream>>>(
        ATT16, nullptr, 0, nullptr, nullptr, 0, WoT, H16, bo, vis,
        DD, DD, DD, DD, 4, 0, 0, 0);
  } else {
    // fallback: row-chunked attention, ATT overwrites Q rows in place
    const int RB = 256;
    float* S32 = (float*)carve((size_t)RB * SS * sizeof(float));
    f16* Pc = (f16*)carve((size_t)RB * SS * sizeof(f16));
    f16* ATT16 = Q16;
    for (int b = 0; b < BB; ++b) {
      for (int r0 = 0; r0 < SS; r0 += RB) {
        gemm8<1><<<dim3((SS / 256) * (RB / 256), 1, 1), blk8, 0, stream>>>(
            Q16 + ((size_t)b * SS + r0) * DD, nullptr, 0, nullptr, nullptr, 0,
            KV16 + (size_t)b * SS * 2 * DD, S32, nullptr, nullptr,
            SS, DD, DD, 2 * DD, SS / 256, 0, 0, 0);
        softmax_rows<<<dim3(RB), blk, 0, stream>>>(S32, Pc);
        gemm8<2><<<dim3((DD / 256) * (RB / 256), 1, 1), blk8, 0, stream>>>(
            Pc, nullptr, 0, nullptr, nullptr, 0, VT16 + (size_t)b * DD * SS,
            ATT16 + ((size_t)b * SS + r0) * DD, nullptr, nullptr,
            DD, SS, SS, SS, DD / 256, 0, 0, 0);
      }
    }
    gemm8<3><<<dim3(4 * 64, 1, 1), blk8, 0, stream>>>(
        ATT16, nullptr, 0, nullptr, nullptr, 0, WoT, H16, bo, vis,
        DD, DD, DD, DD, 4, 0, 0, 0);
  }

  // 9+10. x = relu(h @ W1 + b1); fused dot with W2 -> partials (slot2)
  gemm8<4><<<dim3(4 * 64, 1, 1), blk8, 0, stream>>>(
      H16, nullptr, 0, nullptr, nullptr, 0, W1T, partials, b1, W2,
      DD, DD, DD, DD, 4, 0, 0, 0);

  // 11. out = sum partials + b2
  reduce_out<<<dim3(MTOT / 256), blk, 0, stream>>>(partials, b2, out);
}

// Round 14
// 475.501 us; speedup vs baseline: 6.9360x; 6.9360x over previous
//
#include <hip/hip_runtime.h>
#include <cstdint>
#include <cstddef>

typedef _Float16 f16;
typedef _Float16 f16x8 __attribute__((ext_vector_type(8)));
typedef _Float16 f16x4 __attribute__((ext_vector_type(4)));
typedef float    f32x4 __attribute__((ext_vector_type(4)));

#define AS1 __attribute__((address_space(1)))
#define AS3 __attribute__((address_space(3)))

static constexpr int BB = 8;      // batch
static constexpr int SS = 2048;   // sequence
static constexpr int DD = 1024;   // model dim
static constexpr int MTOT = BB * SS; // 16384

// ---------------------------------------------------------------------------
// fused cast f32->f16 for both inputs + qkv bias concat (one dispatch)
// ---------------------------------------------------------------------------
__global__ __launch_bounds__(256) void cast2_f32_f16(
    const float* __restrict__ s1, const float* __restrict__ s2,
    f16* __restrict__ d1, f16* __restrict__ d2, int n4,
    const float* __restrict__ bq, const float* __restrict__ bk,
    const float* __restrict__ bv, float* __restrict__ qkvb) {
  int i = blockIdx.x * 256 + threadIdx.x;
  if (i < 3 * DD)
    qkvb[i] = (i < DD) ? bq[i] : (i < 2 * DD) ? bk[i - DD] : bv[i - 2 * DD];
  const float* s;
  f16* d;
  int j;
  if (i < n4) { s = s1; d = d1; j = i; }
  else        { s = s2; d = d2; j = i - n4; if (j >= n4) return; }
  const float4 f = reinterpret_cast<const float4*>(s)[j];
  f16x4 o = { (f16)f.x, (f16)f.y, (f16)f.z, (f16)f.w };
  reinterpret_cast<f16x4*>(d)[j] = o;
}

// ---------------------------------------------------------------------------
// fused weight transpose + cast for 5 weights: WT[n][k] = (f16)W[k][n]
// ---------------------------------------------------------------------------
__global__ __launch_bounds__(256) void transpose_cast_wt5(
    const float* __restrict__ W0, const float* __restrict__ W1,
    const float* __restrict__ W2, const float* __restrict__ W3,
    const float* __restrict__ W4,
    f16* __restrict__ D0, f16* __restrict__ D1, f16* __restrict__ D2,
    f16* __restrict__ D3, f16* __restrict__ D4) {
  __shared__ float tile[32][33];
  const float* W;
  f16* Dst;
  switch (blockIdx.z) {
    case 0: W = W0; Dst = D0; break;
    case 1: W = W1; Dst = D1; break;
    case 2: W = W2; Dst = D2; break;
    case 3: W = W3; Dst = D3; break;
    default: W = W4; Dst = D4; break;
  }
  const int bx = blockIdx.x * 32;
  const int by = blockIdx.y * 32;
  const int tx = threadIdx.x & 31;
  const int ty = threadIdx.x >> 5;
  for (int i = ty; i < 32; i += 8) tile[i][tx] = W[(size_t)(by + i) * DD + bx + tx];
  __syncthreads();
  for (int i = ty; i < 32; i += 8)
    Dst[(size_t)(bx + i) * DD + by + tx] = (f16)tile[tx][i];
}

// ---------------------------------------------------------------------------
// batched f16 transpose with src stride: dst[b][c][r] = src[b*sBat + r*sStr + c]
// ---------------------------------------------------------------------------
__global__ __launch_bounds__(256) void transpose_f16_batch(const f16* __restrict__ src,
                                                           f16* __restrict__ dst,
                                                           int R, int C, int sStr,
                                                           size_t sBat) {
  __shared__ f16 tile[32][33];
  src += (size_t)blockIdx.z * sBat;
  dst += (size_t)blockIdx.z * R * C;
  const int bx = blockIdx.x * 32;
  const int by = blockIdx.y * 32;
  const int tx = threadIdx.x & 31;
  const int ty = threadIdx.x >> 5;
  for (int i = ty; i < 32; i += 8) tile[i][tx] = src[(size_t)(by + i) * sStr + bx + tx];
  __syncthreads();
  for (int i = ty; i < 32; i += 8) dst[(size_t)(bx + i) * R + by + tx] = tile[tx][i];
}

// ---------------------------------------------------------------------------
// 256x256 GEMM, 16x16x32 MFMA — r14: r13 retried with the CORRECT bound.
// __launch_bounds__(512,2) is the bound under which this body compiles to
// 128 VGPR / no spill (r8-r12 verified); r13's (512,4) capped the allocator
// at 64 arch VGPRs -> acc spilled to scratch (FETCH 1.77GB, 3% MfmaUtil).
// Single-buffered LDS (64 KB) -> 2 blocks/CU via LDS+VGPR fit (4 waves/SIMD
// x 128 VGPR = full pool). Cross-block anti-phase overlap hypothesis.
// EPI 0: fused QKV | 1 ->f32 | 2 ->f16 | 3 +bias+resid | 4 relu+W2 dot
// ---------------------------------------------------------------------------
template <int EPI>
__global__ __launch_bounds__(512, 2) void gemm8(
    const f16* __restrict__ A, const f16* __restrict__ A2, int zsplit,
    const f16* __restrict__ Aq, void* __restrict__ CoutQ, int qn,
    const f16* __restrict__ BT, void* __restrict__ Cout,
    const float* __restrict__ bias, const float* __restrict__ resid,
    int N, int K, int ldA, int ldB, int gx,
    size_t Abat, size_t Bbat, size_t Cbat) {
  __shared__ f16 smA[256 * 64];
  __shared__ f16 smB[256 * 64];

  const int bz = blockIdx.z;
  const f16* Ab = (zsplit && bz >= zsplit) ? A2 + (size_t)(bz - zsplit) * Abat
                                           : A + (size_t)bz * Abat;
  BT += (size_t)bz * Bbat;

  // bijective XCD swizzle (m204)
  const int nwg = gridDim.x;
  const int q = nwg >> 3, r = nwg & 7;
  const int xcd = blockIdx.x & 7, lin = blockIdx.x >> 3;
  const int wg = (xcd < r ? xcd * (q + 1) : r * (q + 1) + (xcd - r) * q) + lin;
  const int n0 = (wg % gx) * 256;
  const int m0 = (wg / gx) * 256;

  if (EPI == 0 && n0 < qn) Ab = Aq;   // fused projection A-select (wave-uniform)

  const int tid = threadIdx.x;
  const int w = tid >> 6, lane = tid & 63;
  const int wr = w >> 2, wc = w & 3;   // 2 x 4 wave grid
  const int lg = lane >> 4, lr = lane & 15;
  const int nt = K >> 6;               // K-tiles (K multiple of 64)

  f32x4 acc[8][4] = {};
  f16x8 alo[4][2], ahi[4][2], bfr[2][2];

  // stage one 128x64 half-tile; LDS linear dest, source granule pre-swizzled
  auto stageA = [&](int t, int h) {
#pragma unroll
    for (int l = 0; l < 2; ++l) {
      const int cb = l * 512 + w * 64;
      const int c = cb + lane;
      const int rr = c >> 3;
      const int g = (c & 7) ^ (rr & 7);
      const f16* src = Ab + (size_t)(m0 + h * 128 + rr) * ldA + t * 64 + g * 8;
      __builtin_amdgcn_global_load_lds((const AS1 void*)src,
          (AS3 void*)(&smA[(h * 1024 + cb) * 8]), 16, 0, 0);
    }
  };
  auto stageB = [&](int t, int h) {
#pragma unroll
    for (int l = 0; l < 2; ++l) {
      const int cb = l * 512 + w * 64;
      const int c = cb + lane;
      const int rr = c >> 3;
      const int g = (c & 7) ^ (rr & 7);
      const f16* src = BT + (size_t)(n0 + h * 128 + rr) * ldB + t * 64 + g * 8;
      __builtin_amdgcn_global_load_lds((const AS1 void*)src,
          (AS3 void*)(&smB[(h * 1024 + cb) * 8]), 16, 0, 0);
    }
  };
  // r4-verified 16x16 fragment reads (0 bank conflicts measured)
  auto lda = [&](f16x8 (&dst)[4][2], int mh) {
#pragma unroll
    for (int i = 0; i < 4; ++i) {
      const int rrow = wr * 128 + (mh * 4 + i) * 16 + lr;
#pragma unroll
      for (int kh = 0; kh < 2; ++kh) {
        const int kg = (kh * 4 + lg) ^ (rrow & 7);
        dst[i][kh] = *(const f16x8*)(&smA[rrow * 64 + kg * 8]);
      }
    }
  };
  auto ldb = [&](int nh) {
#pragma unroll
    for (int j = 0; j < 2; ++j) {
      const int nrow = wc * 64 + (nh * 2 + j) * 16 + lr;
#pragma unroll
      for (int kh = 0; kh < 2; ++kh) {
        const int kg = (kh * 4 + lg) ^ (nrow & 7);
        bfr[j][kh] = *(const f16x8*)(&smB[nrow * 64 + kg * 8]);
      }
    }
  };
  auto mma = [&](const f16x8 (&a)[4][2], int mh, int nh) {
#pragma unroll
    for (int i = 0; i < 4; ++i)
#pragma unroll
      for (int j = 0; j < 2; ++j)
#pragma unroll
        for (int kh = 0; kh < 2; ++kh)
          acc[mh * 4 + i][nh * 2 + j] = __builtin_amdgcn_mfma_f32_16x16x32_f16(
              a[i][kh], bfr[j][kh], acc[mh * 4 + i][nh * 2 + j], 0, 0, 0);
  };

  // m97-class 2-barrier loop. __syncthreads provides vmcnt(0)+lgkmcnt(0)
  // drains: barrier-1 guarantees staged data landed; barrier-2 guarantees all
  // waves' ds_reads of tile t completed before the buffer is overwritten.
  for (int t = 0; t < nt; ++t) {
    stageA(t, 0); stageA(t, 1);
    stageB(t, 0); stageB(t, 1);
    __syncthreads();
    ldb(0); lda(alo, 0); lda(ahi, 1);
    mma(alo, 0, 0); mma(ahi, 1, 0);
    ldb(1);
    mma(ahi, 1, 1); mma(alo, 0, 1);
    __syncthreads();
  }

  if (EPI == 4) {
    // fused relu + W2 (in `resid`) dot -> partials[16][MTOT] (each written once)
    float* part = (float*)Cout;
    const int cq = (n0 >> 6) + wc;
#pragma unroll
    for (int I = 0; I < 8; ++I) {
#pragma unroll
      for (int rr = 0; rr < 4; ++rr) {
        const int row = m0 + wr * 128 + I * 16 + lg * 4 + rr;
        float s = 0.f;
#pragma unroll
        for (int J = 0; J < 4; ++J) {
          const int col = n0 + wc * 64 + J * 16 + lr;
          float v = acc[I][J][rr] + bias[col];
          v = fmaxf(v, 0.f);
          s += v * resid[col];
        }
#pragma unroll
        for (int o = 1; o < 16; o <<= 1) s += __shfl_xor(s, o);
        if (lr == 0) part[(size_t)cq * MTOT + row] = s;
      }
    }
    return;
  }

  // epilogue: D mapping col=lane&15, row=(lane>>4)*4+r
  const bool isQ = (EPI == 0) && (n0 < qn);
#pragma unroll
  for (int I = 0; I < 8; ++I) {
    const int row = m0 + wr * 128 + I * 16 + lg * 4;
#pragma unroll
    for (int J = 0; J < 4; ++J) {
      const int col = n0 + wc * 64 + J * 16 + lr;
      float bval = 0.f;
      if (EPI == 0 || EPI == 3) bval = bias[col];
#pragma unroll
      for (int rr = 0; rr < 4; ++rr) {
        float v = acc[I][J][rr] + bval;
        if (EPI == 0) {
          if (isQ) ((f16*)CoutQ)[(size_t)(row + rr) * qn + col] = (f16)v;
          else     ((f16*)Cout)[(size_t)(row + rr) * N + (col - qn)] = (f16)v;
        } else {
          const size_t idx = (size_t)(row + rr) * N + col;
          if (EPI == 3) v += resid[idx];
          if (EPI == 1)
            ((float*)Cout)[(size_t)bz * Cbat + idx] = v;
          else
            ((f16*)Cout)[(size_t)bz * Cbat + idx] = (f16)v;
        }
      }
    }
  }
}

// ---------------------------------------------------------------------------
// row softmax: one block per row of 2048 fp32 scores -> f16 probabilities
// ---------------------------------------------------------------------------
__global__ __launch_bounds__(256) void softmax_rows(const float* __restrict__ Sc,
                                                    f16* __restrict__ P) {
  const size_t row = blockIdx.x;
  const float* x = Sc + row * SS;
  f16* p = P + row * SS;
  const int t = threadIdx.x;
  const int wid = t >> 6, lane = t & 63;
  __shared__ float red[8];

  float4 va = reinterpret_cast<const float4*>(x)[t];
  float4 vb = reinterpret_cast<const float4*>(x)[256 + t];
  float mx = fmaxf(fmaxf(fmaxf(va.x, va.y), fmaxf(va.z, va.w)),
                   fmaxf(fmaxf(vb.x, vb.y), fmaxf(vb.z, vb.w)));
#pragma unroll
  for (int o = 32; o >= 1; o >>= 1) mx = fmaxf(mx, __shfl_xor(mx, o));
  if (lane == 0) red[wid] = mx;
  __syncthreads();
  mx = fmaxf(fmaxf(red[0], red[1]), fmaxf(red[2], red[3]));

  va.x = __expf(va.x - mx); va.y = __expf(va.y - mx);
  va.z = __expf(va.z - mx); va.w = __expf(va.w - mx);
  vb.x = __expf(vb.x - mx); vb.y = __expf(vb.y - mx);
  vb.z = __expf(vb.z - mx); vb.w = __expf(vb.w - mx);
  float sum = (va.x + va.y) + (va.z + va.w) + (vb.x + vb.y) + (vb.z + vb.w);
#pragma unroll
  for (int o = 32; o >= 1; o >>= 1) sum += __shfl_xor(sum, o);
  if (lane == 0) red[4 + wid] = sum;
  __syncthreads();
  sum = red[4] + red[5] + red[6] + red[7];
  const float inv = 1.0f / sum;
  f16x4 pa = { (f16)(va.x * inv), (f16)(va.y * inv),
               (f16)(va.z * inv), (f16)(va.w * inv) };
  f16x4 pb = { (f16)(vb.x * inv), (f16)(vb.y * inv),
               (f16)(vb.z * inv), (f16)(vb.w * inv) };
  reinterpret_cast<f16x4*>(p)[t] = pa;
  reinterpret_cast<f16x4*>(p)[256 + t] = pb;
}

// ---------------------------------------------------------------------------
// out[i] = sum_c partials[c][i] + b2
// ---------------------------------------------------------------------------
__global__ __launch_bounds__(256) void reduce_out(const float* __restrict__ part,
                                                  const float* __restrict__ b2,
                                                  float* __restrict__ out) {
  const int i = blockIdx.x * 256 + threadIdx.x;
  float s = 0.f;
#pragma unroll
  for (int c = 0; c < 16; ++c) s += part[(size_t)c * MTOT + i];
  out[i] = s + b2[0];
}

// ---------------------------------------------------------------------------
extern "C" void kernel_launch(void* const* d_in, const int* in_sizes, int n_in,
                              void* d_out, int out_size, void* d_ws, size_t ws_size,
                              hipStream_t stream) {
  const float* vis = (const float*)d_in[0];
  const float* aud = (const float*)d_in[1];
  const float* Wq = (const float*)d_in[2];
  const float* bq = (const float*)d_in[3];
  const float* Wk = (const float*)d_in[4];
  const float* bk = (const float*)d_in[5];
  const float* Wv = (const float*)d_in[6];
  const float* bv = (const float*)d_in[7];
  const float* Wo = (const float*)d_in[8];
  const float* bo = (const float*)d_in[9];
  const float* W1 = (const float*)d_in[10];
  const float* b1 = (const float*)d_in[11];
  const float* W2 = (const float*)d_in[12];
  const float* b2 = (const float*)d_in[13];
  float* out = (float*)d_out;
  (void)in_sizes; (void)n_in; (void)out_size;

  char* ws = (char*)d_ws;
  size_t off = 0;
  auto carve = [&](size_t bytes) -> void* {
    void* p = ws + off;
    off += (bytes + 255) & ~(size_t)255;
    return p;
  };
  const size_t wtB = (size_t)DD * DD * sizeof(f16);     // 2 MB
  const size_t bufB = (size_t)MTOT * DD * sizeof(f16);  // 33.55 MB
  // QKVT rows 0..1023 = Wq^T, 1024..2047 = Wk^T, 2048..3071 = Wv^T
  f16* QKVT = (f16*)carve(3 * wtB);
  f16* WoT = (f16*)carve(wtB);
  f16* W1T = (f16*)carve(wtB);
  float* qkvb = (float*)carve(3 * DD * sizeof(float));  // 12 KB bias concat
  f16* slot1 = (f16*)carve(bufB);    // VIS16 -> VT16 -> H16
  f16* slot2 = (f16*)carve(bufB);    // AUD16 -> P0 -> partials
  f16* slot3 = (f16*)carve(bufB);    // Q16 -> P1 (or ATT in fallback)
  f16* KV16 = (f16*)carve(2 * bufB); // fused K|V projection [16384][2048]

  const size_t rem = (ws_size > off) ? ws_size - off : 0;
  const size_t needMain = (size_t)4 * SS * SS * sizeof(float) + 512; // 67.1 MB

  f16* VIS16 = slot1;
  f16* AUD16 = slot2;
  f16* Q16 = slot3;
  f16* VT16 = slot1;
  f16* P0 = slot2;
  f16* P1 = slot3;
  f16* H16 = slot1;
  float* partials = (float*)slot2;

  const dim3 blk(256);
  const dim3 blk8(512);
  const int n4 = MTOT * DD / 4;

  // 1. cast both inputs to fp16 + build qkv bias concat (one dispatch)
  cast2_f32_f16<<<dim3((2 * n4 + 255) / 256), blk, 0, stream>>>(
      vis, aud, VIS16, AUD16, n4, bq, bk, bv, qkvb);

  // 2. transpose + cast all 5 weights (one dispatch)
  transpose_cast_wt5<<<dim3(DD / 32, DD / 32, 5), blk, 0, stream>>>(
      Wq, Wk, Wv, Wo, W1, QKVT, QKVT + (size_t)DD * DD,
      QKVT + (size_t)2 * DD * DD, WoT, W1T);

  // 3. fused Q|K|V projection: one dispatch, N=3072, A/C select by n0
  gemm8<0><<<dim3(12 * 64, 1, 1), blk8, 0, stream>>>(
      AUD16, nullptr, 0, VIS16, Q16, DD, QKVT, KV16, qkvb, nullptr,
      2 * DD, DD, DD, DD, 12, 0, 0, 0);

  // 4. V -> VT per batch (V = KV16 cols 1024.., row stride 2048)
  transpose_f16_batch<<<dim3(DD / 32, SS / 32, BB), blk, 0, stream>>>(
      KV16 + DD, VT16, SS, DD, 2 * DD, (size_t)SS * 2 * DD);

  if (rem >= needMain) {
    float* S32 = (float*)carve((size_t)4 * SS * SS * sizeof(float)); // 67.1 MB
    f16* ATT16 = (f16*)S32;  // reused after softmax chunk 2 consumes S32
    // 5-6. scores -> softmax, batches 0-3 then 4-7
    gemm8<1><<<dim3((SS / 256) * (SS / 256), 1, 4), blk8, 0, stream>>>(
        Q16, nullptr, 0, nullptr, nullptr, 0, KV16, S32, nullptr, nullptr,
        SS, DD, DD, 2 * DD, SS / 256,
        (size_t)SS * DD, (size_t)SS * 2 * DD, (size_t)SS * SS);
    softmax_rows<<<dim3(4 * SS), blk, 0, stream>>>(S32, P0);
    gemm8<1><<<dim3((SS / 256) * (SS / 256), 1, 4), blk8, 0, stream>>>(
        Q16 + (size_t)4 * SS * DD, nullptr, 0, nullptr, nullptr, 0,
        KV16 + (size_t)4 * SS * 2 * DD, S32, nullptr, nullptr,
        SS, DD, DD, 2 * DD, SS / 256,
        (size_t)SS * DD, (size_t)SS * 2 * DD, (size_t)SS * SS);
    softmax_rows<<<dim3(4 * SS), blk, 0, stream>>>(S32, P1);
    // 7. PV: one full-width dispatch, z=8, split-P A base; ATT overwrites S32
    gemm8<2><<<dim3((DD / 256) * (SS / 256), 1, 8), blk8, 0, stream>>>(
        P0, P1, 4, nullptr, nullptr, 0, VT16, ATT16, nullptr, nullptr,
        DD, SS, SS, SS, DD / 256,
        (size_t)SS * SS, (size_t)DD * SS, (size_t)SS * DD);
    // 8. h = attended @ Wo + bo + visual(residual, fp32) -> slot1 (VT dead)
    gemm8<3><<<dim3(4 * 64, 1, 1), blk8, 0, stream>>>(
        ATT16, nullptr, 0, nullptr, nullptr, 0, WoT, H16, bo, vis,
        DD, DD, DD, DD, 4, 0, 0, 0);
  } else {
    // fallback: row-chunked attention, ATT overwrites Q rows in place
    const int RB = 256;
    float* S32 = (float*)carve((size_t)RB * SS * sizeof(float));
    f16* Pc = (f16*)carve((size_t)RB * SS * sizeof(f16));
    f16* ATT16 = Q16;
    for (int b = 0; b < BB; ++b) {
      for (int r0 = 0; r0 < SS; r0 += RB) {
        gemm8<1><<<dim3((SS / 256) * (RB / 256), 1, 1), blk8, 0, stream>>>(
            Q16 + ((size_t)b * SS + r0) * DD, nullptr, 0, nullptr, nullptr, 0,
            KV16 + (size_t)b * SS * 2 * DD, S32, nullptr, nullptr,
            SS, DD, DD, 2 * DD, SS / 256, 0, 0, 0);
        softmax_rows<<<dim3(RB), blk, 0, stream>>>(S32, Pc);
        gemm8<2><<<dim3((DD / 256) * (RB / 256), 1, 1), blk8, 0, stream>>>(
            Pc, nullptr, 0, nullptr, nullptr, 0, VT16 + (size_t)b * DD * SS,
            ATT16 + ((size_t)b * SS + r0) * DD, nullptr, nullptr,
            DD, SS, SS, SS, DD / 256, 0, 0, 0);
      }
    }
    gemm8<3><<<dim3(4 * 64, 1, 1), blk8, 0, stream>>>(
        ATT16, nullptr, 0, nullptr, nullptr, 0, WoT, H16, bo, vis,
        DD, DD, DD, DD, 4, 0, 0, 0);
  }

  // 9+10. x = relu(h @ W1 + b1); fused dot with W2 -> partials (slot2)
  gemm8<4><<<dim3(4 * 64, 1, 1), blk8, 0, stream>>>(
      H16, nullptr, 0, nullptr, nullptr, 0, W1T, partials, b1, W2,
      DD, DD, DD, DD, 4, 0, 0, 0);

  // 11. out = sum partials + b2
  reduce_out<<<dim3(MTOT / 256), blk, 0, stream>>>(partials, b2, out);
}

// Round 15
// 451.038 us; speedup vs baseline: 7.3122x; 1.0542x over previous
//
#include <hip/hip_runtime.h>
#include <cstdint>
#include <cstddef>

typedef _Float16 f16;
typedef _Float16 f16x8 __attribute__((ext_vector_type(8)));
typedef _Float16 f16x4 __attribute__((ext_vector_type(4)));
typedef float    f32x4 __attribute__((ext_vector_type(4)));

#define AS1 __attribute__((address_space(1)))
#define AS3 __attribute__((address_space(3)))

static constexpr int BB = 8;      // batch
static constexpr int SS = 2048;   // sequence
static constexpr int DD = 1024;   // model dim
static constexpr int MTOT = BB * SS; // 16384

// ---------------------------------------------------------------------------
// fused cast f32->f16 for both inputs + qkv bias concat (one dispatch)
// ---------------------------------------------------------------------------
__global__ __launch_bounds__(256) void cast2_f32_f16(
    const float* __restrict__ s1, const float* __restrict__ s2,
    f16* __restrict__ d1, f16* __restrict__ d2, int n4,
    const float* __restrict__ bq, const float* __restrict__ bk,
    const float* __restrict__ bv, float* __restrict__ qkvb) {
  int i = blockIdx.x * 256 + threadIdx.x;
  if (i < 3 * DD)
    qkvb[i] = (i < DD) ? bq[i] : (i < 2 * DD) ? bk[i - DD] : bv[i - 2 * DD];
  const float* s;
  f16* d;
  int j;
  if (i < n4) { s = s1; d = d1; j = i; }
  else        { s = s2; d = d2; j = i - n4; if (j >= n4) return; }
  const float4 f = reinterpret_cast<const float4*>(s)[j];
  f16x4 o = { (f16)f.x, (f16)f.y, (f16)f.z, (f16)f.w };
  reinterpret_cast<f16x4*>(d)[j] = o;
}

// ---------------------------------------------------------------------------
// fused weight transpose + cast for 5 weights: WT[n][k] = (f16)W[k][n]
// ---------------------------------------------------------------------------
__global__ __launch_bounds__(256) void transpose_cast_wt5(
    const float* __restrict__ W0, const float* __restrict__ W1,
    const float* __restrict__ W2, const float* __restrict__ W3,
    const float* __restrict__ W4,
    f16* __restrict__ D0, f16* __restrict__ D1, f16* __restrict__ D2,
    f16* __restrict__ D3, f16* __restrict__ D4) {
  __shared__ float tile[32][33];
  const float* W;
  f16* Dst;
  switch (blockIdx.z) {
    case 0: W = W0; Dst = D0; break;
    case 1: W = W1; Dst = D1; break;
    case 2: W = W2; Dst = D2; break;
    case 3: W = W3; Dst = D3; break;
    default: W = W4; Dst = D4; break;
  }
  const int bx = blockIdx.x * 32;
  const int by = blockIdx.y * 32;
  const int tx = threadIdx.x & 31;
  const int ty = threadIdx.x >> 5;
  for (int i = ty; i < 32; i += 8) tile[i][tx] = W[(size_t)(by + i) * DD + bx + tx];
  __syncthreads();
  for (int i = ty; i < 32; i += 8)
    Dst[(size_t)(bx + i) * DD + by + tx] = (f16)tile[tx][i];
}

// ---------------------------------------------------------------------------
// batched f16 transpose with src stride: dst[b][c][r] = src[b*sBat + r*sStr + c]
// ---------------------------------------------------------------------------
__global__ __launch_bounds__(256) void transpose_f16_batch(const f16* __restrict__ src,
                                                           f16* __restrict__ dst,
                                                           int R, int C, int sStr,
                                                           size_t sBat) {
  __shared__ f16 tile[32][33];
  src += (size_t)blockIdx.z * sBat;
  dst += (size_t)blockIdx.z * R * C;
  const int bx = blockIdx.x * 32;
  const int by = blockIdx.y * 32;
  const int tx = threadIdx.x & 31;
  const int ty = threadIdx.x >> 5;
  for (int i = ty; i < 32; i += 8) tile[i][tx] = src[(size_t)(by + i) * sStr + bx + tx];
  __syncthreads();
  for (int i = ty; i < 32; i += 8) dst[(size_t)(bx + i) * R + by + tx] = tile[tx][i];
}

// ---------------------------------------------------------------------------
// 4-merged-phase 256x256 GEMM (T1+T2+T4+T5), 16x16x32 MFMA — BEST kernel
// (451.3/451.8 us, r10/r12). At the LDS-read/MFMA overlap limit of the
// 8-wave 256^2 geometry: experiments closed = lgkm removal (null, r9),
// barrier halving (+3%, kept), B-LDS-bypass (-29%, r11), single-buffer
// co-residency (-5%, r13/r14).
// EPI 0: fused QKV | 1 ->f32 | 2 ->f16 | 3 +bias+resid | 4 relu+W2 dot
// ---------------------------------------------------------------------------
template <int EPI>
__global__ __launch_bounds__(512, 2) void gemm8(
    const f16* __restrict__ A, const f16* __restrict__ A2, int zsplit,
    const f16* __restrict__ Aq, void* __restrict__ CoutQ, int qn,
    const f16* __restrict__ BT, void* __restrict__ Cout,
    const float* __restrict__ bias, const float* __restrict__ resid,
    int N, int K, int ldA, int ldB, int gx,
    size_t Abat, size_t Bbat, size_t Cbat) {
  __shared__ f16 smA[2][256 * 64];
  __shared__ f16 smB[2][256 * 64];

  const int bz = blockIdx.z;
  const f16* Ab = (zsplit && bz >= zsplit) ? A2 + (size_t)(bz - zsplit) * Abat
                                           : A + (size_t)bz * Abat;
  BT += (size_t)bz * Bbat;

  // bijective XCD swizzle (m204)
  const int nwg = gridDim.x;
  const int q = nwg >> 3, r = nwg & 7;
  const int xcd = blockIdx.x & 7, lin = blockIdx.x >> 3;
  const int wg = (xcd < r ? xcd * (q + 1) : r * (q + 1) + (xcd - r) * q) + lin;
  const int n0 = (wg % gx) * 256;
  const int m0 = (wg / gx) * 256;

  if (EPI == 0 && n0 < qn) Ab = Aq;   // fused projection A-select (wave-uniform)

  const int tid = threadIdx.x;
  const int w = tid >> 6, lane = tid & 63;
  const int wr = w >> 2, wc = w & 3;   // 2 x 4 wave grid
  const int lg = lane >> 4, lr = lane & 15;
  const int nt = K >> 6;               // K-tiles (K multiple of 128)

  f32x4 acc[8][4] = {};
  f16x8 alo[4][2], ahi[4][2], bfr[2][2];

  // stage one 128x64 half-tile; LDS linear dest, source granule pre-swizzled
  auto stageA = [&](int t, int h, int d) {
#pragma unroll
    for (int l = 0; l < 2; ++l) {
      const int cb = l * 512 + w * 64;
      const int c = cb + lane;
      const int rr = c >> 3;
      const int g = (c & 7) ^ (rr & 7);
      const f16* src = Ab + (size_t)(m0 + h * 128 + rr) * ldA + t * 64 + g * 8;
      __builtin_amdgcn_global_load_lds((const AS1 void*)src,
          (AS3 void*)(&smA[d][(h * 1024 + cb) * 8]), 16, 0, 0);
    }
  };
  auto stageB = [&](int t, int h, int d) {
#pragma unroll
    for (int l = 0; l < 2; ++l) {
      const int cb = l * 512 + w * 64;
      const int c = cb + lane;
      const int rr = c >> 3;
      const int g = (c & 7) ^ (rr & 7);
      const f16* src = BT + (size_t)(n0 + h * 128 + rr) * ldB + t * 64 + g * 8;
      __builtin_amdgcn_global_load_lds((const AS1 void*)src,
          (AS3 void*)(&smB[d][(h * 1024 + cb) * 8]), 16, 0, 0);
    }
  };
  // r4-verified 16x16 fragment reads (0 bank conflicts measured)
  auto lda = [&](f16x8 (&dst)[4][2], int mh, int d) {
#pragma unroll
    for (int i = 0; i < 4; ++i) {
      const int rrow = wr * 128 + (mh * 4 + i) * 16 + lr;
#pragma unroll
      for (int kh = 0; kh < 2; ++kh) {
        const int kg = (kh * 4 + lg) ^ (rrow & 7);
        dst[i][kh] = *(const f16x8*)(&smA[d][rrow * 64 + kg * 8]);
      }
    }
  };
  auto ldb = [&](int nh, int d) {
#pragma unroll
    for (int j = 0; j < 2; ++j) {
      const int nrow = wc * 64 + (nh * 2 + j) * 16 + lr;
#pragma unroll
      for (int kh = 0; kh < 2; ++kh) {
        const int kg = (kh * 4 + lg) ^ (nrow & 7);
        bfr[j][kh] = *(const f16x8*)(&smB[d][nrow * 64 + kg * 8]);
      }
    }
  };
  auto mma = [&](const f16x8 (&a)[4][2], int mh, int nh) {
#pragma unroll
    for (int i = 0; i < 4; ++i)
#pragma unroll
      for (int j = 0; j < 2; ++j)
#pragma unroll
        for (int kh = 0; kh < 2; ++kh)
          acc[mh * 4 + i][nh * 2 + j] = __builtin_amdgcn_mfma_f32_16x16x32_f16(
              a[i][kh], bfr[j][kh], acc[mh * 4 + i][nh * 2 + j], 0, 0, 0);
  };

#define PH_MID()                                                     \
  __builtin_amdgcn_sched_barrier(0);                                 \
  __builtin_amdgcn_s_barrier();                                      \
  __builtin_amdgcn_sched_barrier(0);                                 \
  __builtin_amdgcn_s_setprio(1)
#define PH_END()                                                     \
  __builtin_amdgcn_s_setprio(0);                                     \
  __builtin_amdgcn_sched_barrier(0);                                 \
  __builtin_amdgcn_s_barrier();                                      \
  __builtin_amdgcn_sched_barrier(0)
#define PH_END_VM4()                                                 \
  __builtin_amdgcn_s_setprio(0);                                     \
  __builtin_amdgcn_sched_barrier(0);                                 \
  asm volatile("s_waitcnt vmcnt(4)" ::: "memory");                   \
  __builtin_amdgcn_sched_barrier(0);                                 \
  __builtin_amdgcn_s_barrier();                                      \
  __builtin_amdgcn_sched_barrier(0)
#define PH_END_VM0()                                                 \
  __builtin_amdgcn_s_setprio(0);                                     \
  __builtin_amdgcn_sched_barrier(0);                                 \
  asm volatile("s_waitcnt vmcnt(0)" ::: "memory");                   \
  __builtin_amdgcn_sched_barrier(0);                                 \
  __builtin_amdgcn_s_barrier();                                      \
  __builtin_amdgcn_sched_barrier(0)

  // prologue: A(0),B(0)->buf0 (8 loads); A(1)->buf1 (4); wait oldest 8
  stageA(0, 0, 0); stageA(0, 1, 0);
  stageB(0, 0, 0); stageB(0, 1, 0);
  if (nt > 1) { stageA(1, 0, 1); stageA(1, 1, 1); }
  asm volatile("s_waitcnt vmcnt(4)" ::: "memory");
  __builtin_amdgcn_sched_barrier(0);
  __builtin_amdgcn_s_barrier();
  __builtin_amdgcn_sched_barrier(0);

  for (int t = 0; t < nt; t += 2) {
    const int u = t + 1;
    const bool pok = (t + 2 < nt);
    // M1: reads tile t (buf0) A+B0; stages B(u)->buf1
    ldb(0, 0); lda(alo, 0, 0); lda(ahi, 1, 0);
    stageB(u, 0, 1); stageB(u, 1, 1);
    PH_MID(); mma(alo, 0, 0); mma(ahi, 1, 0); PH_END();
    // M2: reads tile t B1; stages A(t+2)->buf0; gate tile u (vmcnt(4))
    ldb(1, 0);
    if (pok) { stageA(t + 2, 0, 0); stageA(t + 2, 1, 0); }
    PH_MID(); mma(ahi, 1, 1); mma(alo, 0, 1);
    if (pok) { PH_END_VM4(); } else { PH_END_VM0(); }
    // M3: reads tile u (buf1) A+B0; stages B(t+2)->buf0
    ldb(0, 1); lda(alo, 0, 1); lda(ahi, 1, 1);
    if (pok) { stageB(t + 2, 0, 0); stageB(t + 2, 1, 0); }
    PH_MID(); mma(alo, 0, 0); mma(ahi, 1, 0); PH_END();
    // M4: reads tile u B1; stages A(t+3)->buf1; gate tile t+2 (vmcnt(4))
    ldb(1, 1);
    if (pok) { stageA(t + 3, 0, 1); stageA(t + 3, 1, 1); }
    PH_MID(); mma(ahi, 1, 1); mma(alo, 0, 1);
    if (pok) { PH_END_VM4(); } else { PH_END(); }
  }
#undef PH_MID
#undef PH_END
#undef PH_END_VM4
#undef PH_END_VM0

  if (EPI == 4) {
    // fused relu + W2 (in `resid`) dot -> partials[16][MTOT] (each written once)
    float* part = (float*)Cout;
    const int cq = (n0 >> 6) + wc;
#pragma unroll
    for (int I = 0; I < 8; ++I) {
#pragma unroll
      for (int rr = 0; rr < 4; ++rr) {
        const int row = m0 + wr * 128 + I * 16 + lg * 4 + rr;
        float s = 0.f;
#pragma unroll
        for (int J = 0; J < 4; ++J) {
          const int col = n0 + wc * 64 + J * 16 + lr;
          float v = acc[I][J][rr] + bias[col];
          v = fmaxf(v, 0.f);
          s += v * resid[col];
        }
#pragma unroll
        for (int o = 1; o < 16; o <<= 1) s += __shfl_xor(s, o);
        if (lr == 0) part[(size_t)cq * MTOT + row] = s;
      }
    }
    return;
  }

  // epilogue: D mapping col=lane&15, row=(lane>>4)*4+r
  const bool isQ = (EPI == 0) && (n0 < qn);
#pragma unroll
  for (int I = 0; I < 8; ++I) {
    const int row = m0 + wr * 128 + I * 16 + lg * 4;
#pragma unroll
    for (int J = 0; J < 4; ++J) {
      const int col = n0 + wc * 64 + J * 16 + lr;
      float bval = 0.f;
      if (EPI == 0 || EPI == 3) bval = bias[col];
#pragma unroll
      for (int rr = 0; rr < 4; ++rr) {
        float v = acc[I][J][rr] + bval;
        if (EPI == 0) {
          if (isQ) ((f16*)CoutQ)[(size_t)(row + rr) * qn + col] = (f16)v;
          else     ((f16*)Cout)[(size_t)(row + rr) * N + (col - qn)] = (f16)v;
        } else {
          const size_t idx = (size_t)(row + rr) * N + col;
          if (EPI == 3) v += resid[idx];
          if (EPI == 1)
            ((float*)Cout)[(size_t)bz * Cbat + idx] = v;
          else
            ((f16*)Cout)[(size_t)bz * Cbat + idx] = (f16)v;
        }
      }
    }
  }
}

// ---------------------------------------------------------------------------
// row softmax: one block per row of 2048 fp32 scores -> f16 probabilities
// ---------------------------------------------------------------------------
__global__ __launch_bounds__(256) void softmax_rows(const float* __restrict__ Sc,
                                                    f16* __restrict__ P) {
  const size_t row = blockIdx.x;
  const float* x = Sc + row * SS;
  f16* p = P + row * SS;
  const int t = threadIdx.x;
  const int wid = t >> 6, lane = t & 63;
  __shared__ float red[8];

  float4 va = reinterpret_cast<const float4*>(x)[t];
  float4 vb = reinterpret_cast<const float4*>(x)[256 + t];
  float mx = fmaxf(fmaxf(fmaxf(va.x, va.y), fmaxf(va.z, va.w)),
                   fmaxf(fmaxf(vb.x, vb.y), fmaxf(vb.z, vb.w)));
#pragma unroll
  for (int o = 32; o >= 1; o >>= 1) mx = fmaxf(mx, __shfl_xor(mx, o));
  if (lane == 0) red[wid] = mx;
  __syncthreads();
  mx = fmaxf(fmaxf(red[0], red[1]), fmaxf(red[2], red[3]));

  va.x = __expf(va.x - mx); va.y = __expf(va.y - mx);
  va.z = __expf(va.z - mx); va.w = __expf(va.w - mx);
  vb.x = __expf(vb.x - mx); vb.y = __expf(vb.y - mx);
  vb.z = __expf(vb.z - mx); vb.w = __expf(vb.w - mx);
  float sum = (va.x + va.y) + (va.z + va.w) + (vb.x + vb.y) + (vb.z + vb.w);
#pragma unroll
  for (int o = 32; o >= 1; o >>= 1) sum += __shfl_xor(sum, o);
  if (lane == 0) red[4 + wid] = sum;
  __syncthreads();
  sum = red[4] + red[5] + red[6] + red[7];
  const float inv = 1.0f / sum;
  f16x4 pa = { (f16)(va.x * inv), (f16)(va.y * inv),
               (f16)(va.z * inv), (f16)(va.w * inv) };
  f16x4 pb = { (f16)(vb.x * inv), (f16)(vb.y * inv),
               (f16)(vb.z * inv), (f16)(vb.w * inv) };
  reinterpret_cast<f16x4*>(p)[t] = pa;
  reinterpret_cast<f16x4*>(p)[256 + t] = pb;
}

// ---------------------------------------------------------------------------
// out[i] = sum_c partials[c][i] + b2
// ---------------------------------------------------------------------------
__global__ __launch_bounds__(256) void reduce_out(const float* __restrict__ part,
                                                  const float* __restrict__ b2,
                                                  float* __restrict__ out) {
  const int i = blockIdx.x * 256 + threadIdx.x;
  float s = 0.f;
#pragma unroll
  for (int c = 0; c < 16; ++c) s += part[(size_t)c * MTOT + i];
  out[i] = s + b2[0];
}

// ---------------------------------------------------------------------------
extern "C" void kernel_launch(void* const* d_in, const int* in_sizes, int n_in,
                              void* d_out, int out_size, void* d_ws, size_t ws_size,
                              hipStream_t stream) {
  const float* vis = (const float*)d_in[0];
  const float* aud = (const float*)d_in[1];
  const float* Wq = (const float*)d_in[2];
  const float* bq = (const float*)d_in[3];
  const float* Wk = (const float*)d_in[4];
  const float* bk = (const float*)d_in[5];
  const float* Wv = (const float*)d_in[6];
  const float* bv = (const float*)d_in[7];
  const float* Wo = (const float*)d_in[8];
  const float* bo = (const float*)d_in[9];
  const float* W1 = (const float*)d_in[10];
  const float* b1 = (const float*)d_in[11];
  const float* W2 = (const float*)d_in[12];
  const float* b2 = (const float*)d_in[13];
  float* out = (float*)d_out;
  (void)in_sizes; (void)n_in; (void)out_size;

  char* ws = (char*)d_ws;
  size_t off = 0;
  auto carve = [&](size_t bytes) -> void* {
    void* p = ws + off;
    off += (bytes + 255) & ~(size_t)255;
    return p;
  };
  const size_t wtB = (size_t)DD * DD * sizeof(f16);     // 2 MB
  const size_t bufB = (size_t)MTOT * DD * sizeof(f16);  // 33.55 MB
  // QKVT rows 0..1023 = Wq^T, 1024..2047 = Wk^T, 2048..3071 = Wv^T
  f16* QKVT = (f16*)carve(3 * wtB);
  f16* WoT = (f16*)carve(wtB);
  f16* W1T = (f16*)carve(wtB);
  float* qkvb = (float*)carve(3 * DD * sizeof(float));  // 12 KB bias concat
  f16* slot1 = (f16*)carve(bufB);    // VIS16 -> VT16 -> H16
  f16* slot2 = (f16*)carve(bufB);    // AUD16 -> P0 -> partials
  f16* slot3 = (f16*)carve(bufB);    // Q16 -> P1 (or ATT in fallback)
  f16* KV16 = (f16*)carve(2 * bufB); // fused K|V projection [16384][2048]

  const size_t rem = (ws_size > off) ? ws_size - off : 0;
  const size_t needMain = (size_t)4 * SS * SS * sizeof(float) + 512; // 67.1 MB

  f16* VIS16 = slot1;
  f16* AUD16 = slot2;
  f16* Q16 = slot3;
  f16* VT16 = slot1;
  f16* P0 = slot2;
  f16* P1 = slot3;
  f16* H16 = slot1;
  float* partials = (float*)slot2;

  const dim3 blk(256);
  const dim3 blk8(512);
  const int n4 = MTOT * DD / 4;

  // 1. cast both inputs to fp16 + build qkv bias concat (one dispatch)
  cast2_f32_f16<<<dim3((2 * n4 + 255) / 256), blk, 0, stream>>>(
      vis, aud, VIS16, AUD16, n4, bq, bk, bv, qkvb);

  // 2. transpose + cast all 5 weights (one dispatch)
  transpose_cast_wt5<<<dim3(DD / 32, DD / 32, 5), blk, 0, stream>>>(
      Wq, Wk, Wv, Wo, W1, QKVT, QKVT + (size_t)DD * DD,
      QKVT + (size_t)2 * DD * DD, WoT, W1T);

  // 3. fused Q|K|V projection: one dispatch, N=3072, A/C select by n0
  gemm8<0><<<dim3(12 * 64, 1, 1), blk8, 0, stream>>>(
      AUD16, nullptr, 0, VIS16, Q16, DD, QKVT, KV16, qkvb, nullptr,
      2 * DD, DD, DD, DD, 12, 0, 0, 0);

  // 4. V -> VT per batch (V = KV16 cols 1024.., row stride 2048)
  transpose_f16_batch<<<dim3(DD / 32, SS / 32, BB), blk, 0, stream>>>(
      KV16 + DD, VT16, SS, DD, 2 * DD, (size_t)SS * 2 * DD);

  if (rem >= needMain) {
    float* S32 = (float*)carve((size_t)4 * SS * SS * sizeof(float)); // 67.1 MB
    f16* ATT16 = (f16*)S32;  // reused after softmax chunk 2 consumes S32
    // 5-6. scores -> softmax, batches 0-3 then 4-7
    gemm8<1><<<dim3((SS / 256) * (SS / 256), 1, 4), blk8, 0, stream>>>(
        Q16, nullptr, 0, nullptr, nullptr, 0, KV16, S32, nullptr, nullptr,
        SS, DD, DD, 2 * DD, SS / 256,
        (size_t)SS * DD, (size_t)SS * 2 * DD, (size_t)SS * SS);
    softmax_rows<<<dim3(4 * SS), blk, 0, stream>>>(S32, P0);
    gemm8<1><<<dim3((SS / 256) * (SS / 256), 1, 4), blk8, 0, stream>>>(
        Q16 + (size_t)4 * SS * DD, nullptr, 0, nullptr, nullptr, 0,
        KV16 + (size_t)4 * SS * 2 * DD, S32, nullptr, nullptr,
        SS, DD, DD, 2 * DD, SS / 256,
        (size_t)SS * DD, (size_t)SS * 2 * DD, (size_t)SS * SS);
    softmax_rows<<<dim3(4 * SS), blk, 0, stream>>>(S32, P1);
    // 7. PV: one full-width dispatch, z=8, split-P A base; ATT overwrites S32
    gemm8<2><<<dim3((DD / 256) * (SS / 256), 1, 8), blk8, 0, stream>>>(
        P0, P1, 4, nullptr, nullptr, 0, VT16, ATT16, nullptr, nullptr,
        DD, SS, SS, SS, DD / 256,
        (size_t)SS * SS, (size_t)DD * SS, (size_t)SS * DD);
    // 8. h = attended @ Wo + bo + visual(residual, fp32) -> slot1 (VT dead)
    gemm8<3><<<dim3(4 * 64, 1, 1), blk8, 0, stream>>>(
        ATT16, nullptr, 0, nullptr, nullptr, 0, WoT, H16, bo, vis,
        DD, DD, DD, DD, 4, 0, 0, 0);
  } else {
    // fallback: row-chunked attention, ATT overwrites Q rows in place
    const int RB = 256;
    float* S32 = (float*)carve((size_t)RB * SS * sizeof(float));
    f16* Pc = (f16*)carve((size_t)RB * SS * sizeof(f16));
    f16* ATT16 = Q16;
    for (int b = 0; b < BB; ++b) {
      for (int r0 = 0; r0 < SS; r0 += RB) {
        gemm8<1><<<dim3((SS / 256) * (RB / 256), 1, 1), blk8, 0, stream>>>(
            Q16 + ((size_t)b * SS + r0) * DD, nullptr, 0, nullptr, nullptr, 0,
            KV16 + (size_t)b * SS * 2 * DD, S32, nullptr, nullptr,
            SS, DD, DD, 2 * DD, SS / 256, 0, 0, 0);
        softmax_rows<<<dim3(RB), blk, 0, stream>>>(S32, Pc);
        gemm8<2><<<dim3((DD / 256) * (RB / 256), 1, 1), blk8, 0, stream>>>(
            Pc, nullptr, 0, nullptr, nullptr, 0, VT16 + (size_t)b * DD * SS,
            ATT16 + ((size_t)b * SS + r0) * DD, nullptr, nullptr,
            DD, SS, SS, SS, DD / 256, 0, 0, 0);
      }
    }
    gemm8<3><<<dim3(4 * 64, 1, 1), blk8, 0, stream>>>(
        ATT16, nullptr, 0, nullptr, nullptr, 0, WoT, H16, bo, vis,
        DD, DD, DD, DD, 4, 0, 0, 0);
  }

  // 9+10. x = relu(h @ W1 + b1); fused dot with W2 -> partials (slot2)
  gemm8<4><<<dim3(4 * 64, 1, 1), blk8, 0, stream>>>(
      H16, nullptr, 0, nullptr, nullptr, 0, W1T, partials, b1, W2,
      DD, DD, DD, DD, 4, 0, 0, 0);

  // 11. out = sum partials + b2
  reduce_out<<<dim3(MTOT / 256), blk, 0, stream>>>(partials, b2, out);
}